// Round 2
// baseline (570.087 us; speedup 1.0000x reference)
//
#include <hip/hip_runtime.h>
#include <hip/hip_bf16.h>
#include <math.h>

#define NTOK 8192
#define HD 1024
#define ID 4096
#define NE 8
#define MAXTILES 40   // 256-row token tiles: <= 32 full + 7 partial
#define SORTT 512
#define TPT (NTOK / SORTT)  // 16 tokens per sort thread

typedef __attribute__((ext_vector_type(8))) short short8;
typedef __attribute__((ext_vector_type(8))) unsigned short ushort8;
typedef __attribute__((ext_vector_type(4))) float floatx4;

__device__ __forceinline__ unsigned short f2bf(float f) {
  unsigned int u = __float_as_uint(f);
  return (unsigned short)((u + 0x7fffu + ((u >> 16) & 1u)) >> 16);
}

__device__ __forceinline__ void async_ld16(const void* g, void* l) {
  __builtin_amdgcn_global_load_lds(
      (const __attribute__((address_space(1))) unsigned int*)g,
      (__attribute__((address_space(3))) unsigned int*)l,
      16, 0, 0);
}

// ---------------- small kernels (unchanged) ----------------

__global__ void transpose_cast_kernel(const float* __restrict__ src,
                                      unsigned short* __restrict__ dst, int R, int C) {
  size_t bo = (size_t)blockIdx.z * R * C;
  src += bo; dst += bo;
  __shared__ float t[64][65];
  int c0 = blockIdx.x * 64, r0 = blockIdx.y * 64;
  int tid = threadIdx.x;
  int rr = tid >> 4, c4 = (tid & 15) * 4;
#pragma unroll
  for (int q = 0; q < 4; q++) {
    int r = rr + q * 16;
    float4 v = *(const float4*)(src + (size_t)(r0 + r) * C + c0 + c4);
    t[r][c4] = v.x; t[r][c4 + 1] = v.y; t[r][c4 + 2] = v.z; t[r][c4 + 3] = v.w;
  }
  __syncthreads();
  int r8 = (tid & 7) * 8;
#pragma unroll
  for (int q = 0; q < 2; q++) {
    int cc = (tid >> 3) + q * 32;
    ushort8 o;
#pragma unroll
    for (int i = 0; i < 8; i++) o[i] = f2bf(t[r8 + i][cc]);
    *(ushort8*)(dst + (size_t)(c0 + cc) * R + r0 + r8) = o;
  }
}

__global__ void router_kernel(const float* __restrict__ x, const float* __restrict__ wr,
                              int* __restrict__ eidx, unsigned short* __restrict__ xb) {
  int wave = threadIdx.x >> 6, lane = threadIdx.x & 63;
  int n = blockIdx.x * 4 + wave;
  const float* xr = x + (size_t)n * HD;
  unsigned short* xbr = xb + (size_t)n * HD;
  double acc[NE];
#pragma unroll
  for (int e = 0; e < NE; e++) acc[e] = 0.0;
#pragma unroll
  for (int v = 0; v < 4; v++) {
    int h = (lane + v * 64) * 4;
    float4 xv = *(const float4*)(xr + h);
    ushort4 o;
    o.x = f2bf(xv.x); o.y = f2bf(xv.y); o.z = f2bf(xv.z); o.w = f2bf(xv.w);
    *(ushort4*)(xbr + h) = o;
#pragma unroll
    for (int e = 0; e < NE; e++) {
      float4 wv = *(const float4*)(wr + e * HD + h);
      acc[e] += (double)xv.x * wv.x + (double)xv.y * wv.y +
                (double)xv.z * wv.z + (double)xv.w * wv.w;
    }
  }
#pragma unroll
  for (int m = 32; m >= 1; m >>= 1) {
#pragma unroll
    for (int e = 0; e < NE; e++) acc[e] += __shfl_xor(acc[e], m, 64);
  }
  if (lane == 0) {
    int best = 0; double bv = acc[0];
#pragma unroll
    for (int e = 1; e < NE; e++) if (acc[e] > bv) { bv = acc[e]; best = e; }
    eidx[n] = best;
  }
}

// counting sort; now emits 256-row tiles for the 256x256 GEMM.
__global__ __launch_bounds__(SORTT) void sort_kernel(
    const int* __restrict__ eidx, int* __restrict__ ntiles, int* __restrict__ tile_e,
    int* __restrict__ tile_base, int* __restrict__ tile_len, int* __restrict__ perm) {
  __shared__ int h[NE][SORTT];
  __shared__ int off_sh[NE];
  __shared__ int tot[NE];
  int t = threadIdx.x;
  int wave = t >> 6, lane = t & 63;
  const int base = t * TPT;

  int4 e0 = *(const int4*)(eidx + base);
  int4 e1 = *(const int4*)(eidx + base + 4);
  int4 e2 = *(const int4*)(eidx + base + 8);
  int4 e3 = *(const int4*)(eidx + base + 12);
  int ex[TPT] = {e0.x, e0.y, e0.z, e0.w, e1.x, e1.y, e1.z, e1.w,
                 e2.x, e2.y, e2.z, e2.w, e3.x, e3.y, e3.z, e3.w};
  int cnt0 = 0, cnt1 = 0, cnt2 = 0, cnt3 = 0, cnt4 = 0, cnt5 = 0, cnt6 = 0, cnt7 = 0;
#pragma unroll
  for (int i = 0; i < TPT; i++) {
    int e = ex[i];
    cnt0 += (e == 0); cnt1 += (e == 1); cnt2 += (e == 2); cnt3 += (e == 3);
    cnt4 += (e == 4); cnt5 += (e == 5); cnt6 += (e == 6); cnt7 += (e == 7);
  }
  h[0][t] = cnt0; h[1][t] = cnt1; h[2][t] = cnt2; h[3][t] = cnt3;
  h[4][t] = cnt4; h[5][t] = cnt5; h[6][t] = cnt6; h[7][t] = cnt7;
  __syncthreads();

  {
    int e = wave;
    int v[8], s = 0;
#pragma unroll
    for (int i = 0; i < 8; i++) { v[i] = h[e][lane * 8 + i]; s += v[i]; }
    int inc = s;
#pragma unroll
    for (int d = 1; d < 64; d <<= 1) {
      int o = __shfl_up(inc, d, 64);
      if (lane >= d) inc += o;
    }
    int exc = inc - s;
#pragma unroll
    for (int i = 0; i < 8; i++) { h[e][lane * 8 + i] = exc; exc += v[i]; }
    if (lane == 63) tot[e] = inc;
  }
  __syncthreads();

  if (t == 0) {
    int s = 0, tt = 0;
    for (int e = 0; e < NE; e++) {
      off_sh[e] = s;
      int c = tot[e];
      for (int b = 0; b < c; b += 256) {
        tile_e[tt] = e;
        tile_base[tt] = s + b;
        tile_len[tt] = (c - b < 256) ? (c - b) : 256;
        tt++;
      }
      s += c;
    }
    *ntiles = tt;
  }
  __syncthreads();

  int c0c = off_sh[0] + h[0][t], c1c = off_sh[1] + h[1][t];
  int c2c = off_sh[2] + h[2][t], c3c = off_sh[3] + h[3][t];
  int c4c = off_sh[4] + h[4][t], c5c = off_sh[5] + h[5][t];
  int c6c = off_sh[6] + h[6][t], c7c = off_sh[7] + h[7][t];
#pragma unroll
  for (int i = 0; i < TPT; i++) {
    int e = ex[i];
    int pos = c0c;
    pos = (e == 1) ? c1c : pos; pos = (e == 2) ? c2c : pos;
    pos = (e == 3) ? c3c : pos; pos = (e == 4) ? c4c : pos;
    pos = (e == 5) ? c5c : pos; pos = (e == 6) ? c6c : pos;
    pos = (e == 7) ? c7c : pos;
    perm[pos] = base + i;
    c0c += (e == 0); c1c += (e == 1); c2c += (e == 2); c3c += (e == 3);
    c4c += (e == 4); c5c += (e == 5); c6c += (e == 6); c7c += (e == 7);
  }
}

// ---------------- 8-phase 256x256 GEMM core (T3+T4+T5) ----------------
// BM=BN=256, BK=64, 512 threads = 8 waves (2M x 4N), per-wave C = 128x64,
// acc[8][4] 16x16x32 frags. LDS: A,B each 2 x 32KB K-tile buffers = 128KB.
// Even K-tiles -> buf0, odd -> buf1. Layout [row][64] bf16 with 16B chunks
// XOR-swizzled by (row&7); staged via global_load_lds from pre-swizzled
// global addresses (conflict-free both sides, measured R1-R4).
//
// Schedule per iteration u (kt0=2u, kt1=2u+1), 8 phases; each phase:
// {4 a-frag ds_reads (+8 b-frag at P1/P5) ; 2 gload_lds stage ; barrier ;
//  setprio1 ; 16 MFMA ; setprio0 ; [vmcnt @P4/P8] ; barrier}.
// Stage slots: P1:SA_late(kt1)  P2:SB1(kt0+2) P3:SB2(kt0+2) P4:SA_early(kt0+2)
//              P5:SA_late(kt0+2) P6:SB1(kt0+3) P7:SB2(kt0+3) P8:SA_early(kt0+3)
// Invariants (hand-verified):
//  WAR: every stage is issued >=1 barrier after the last ds_read of its
//       region (A q0/q2 consumed by P2/P6, q1/q3 by P4/P8, B by P1/P5).
//  Landing: steady-state 14 outstanding at P4/P8; vmcnt(6) completes the
//       oldest 8 = exactly the next K-tile's full data. Last iteration
//       uses vmcnt(0) at P4 (tail has no new issues to push the window).

#define VMC6() asm volatile("s_waitcnt vmcnt(6)" ::: "memory")
#define VMC0() asm volatile("s_waitcnt vmcnt(0)" ::: "memory")
#define NOPS ((void)0)

#define SA8(BUF, kt, q) \
  async_ld16(gAq[q] + (size_t)(kt) * 64, lA + ((BUF) * 16384 + ((q) * 64 + wave * 8) * 64))
#define SB8(BUF, kt, q) \
  async_ld16(gBq[q] + (size_t)(kt) * 64, lB + ((BUF) * 16384 + ((q) * 64 + wave * 8) * 64))

#define MF4(AV, KK, I)                                                                       \
  acc[I][0] = __builtin_amdgcn_mfma_f32_16x16x32_bf16(AV, bf[0][KK], acc[I][0], 0, 0, 0);    \
  acc[I][1] = __builtin_amdgcn_mfma_f32_16x16x32_bf16(AV, bf[1][KK], acc[I][1], 0, 0, 0);    \
  acc[I][2] = __builtin_amdgcn_mfma_f32_16x16x32_bf16(AV, bf[2][KK], acc[I][2], 0, 0, 0);    \
  acc[I][3] = __builtin_amdgcn_mfma_f32_16x16x32_bf16(AV, bf[3][KK], acc[I][3], 0, 0, 0);

#define PH8(BT, I, STG, TAIL)                                                  \
  {                                                                            \
    short8 a0k0 = *(const short8*)(lA + (BT) * 16384 + aoff[I] + sx0);         \
    short8 a0k1 = *(const short8*)(lA + (BT) * 16384 + aoff[I] + sx1);         \
    short8 a1k0 = *(const short8*)(lA + (BT) * 16384 + aoff[(I) + 1] + sx0);   \
    short8 a1k1 = *(const short8*)(lA + (BT) * 16384 + aoff[(I) + 1] + sx1);   \
    STG;                                                                       \
    __builtin_amdgcn_s_barrier();                                              \
    __builtin_amdgcn_s_setprio(1);                                             \
    MF4(a0k0, 0, I) MF4(a0k1, 1, I)                                            \
    MF4(a1k0, 0, (I) + 1) MF4(a1k1, 1, (I) + 1)                                \
    __builtin_amdgcn_s_setprio(0);                                             \
    TAIL;                                                                      \
    __builtin_amdgcn_s_barrier();                                              \
  }

#define LOADB8(BT)                                                             \
  bf[0][0] = *(const short8*)(lB + (BT) * 16384 + boff[0] + sx0);              \
  bf[0][1] = *(const short8*)(lB + (BT) * 16384 + boff[0] + sx1);              \
  bf[1][0] = *(const short8*)(lB + (BT) * 16384 + boff[1] + sx0);              \
  bf[1][1] = *(const short8*)(lB + (BT) * 16384 + boff[1] + sx1);              \
  bf[2][0] = *(const short8*)(lB + (BT) * 16384 + boff[2] + sx0);              \
  bf[2][1] = *(const short8*)(lB + (BT) * 16384 + boff[2] + sx1);              \
  bf[3][0] = *(const short8*)(lB + (BT) * 16384 + boff[3] + sx0);              \
  bf[3][1] = *(const short8*)(lB + (BT) * 16384 + boff[3] + sx1);

template <int NK>
__device__ __forceinline__ void gemm8phase(const unsigned short* const* gAq,
                                           const unsigned short* const* gBq,
                                           unsigned short* lA, unsigned short* lB,
                                           int wave, int lane, floatx4 (&acc)[8][4]) {
  int c15 = lane & 15, q4 = lane >> 4, c7 = c15 & 7;
  int wm = wave >> 2, wn = wave & 3;
  int sx0 = (q4 ^ c7) * 8;        // kk=0 swizzled chunk (shorts)
  int sx1 = ((4 + q4) ^ c7) * 8;  // kk=1
  int aoff[8], boff[4];
#pragma unroll
  for (int i = 0; i < 8; i++) aoff[i] = (wm * 128 + i * 16 + c15) * 64;
#pragma unroll
  for (int j = 0; j < 4; j++) boff[j] = (wn * 64 + j * 16 + c15) * 64;

  // prologue: tile0 (all 8, oldest), then tile1 B + A-early (6 newest)
  SB8(0, 0, 0); SB8(0, 0, 1); SB8(0, 0, 2); SB8(0, 0, 3);
  SA8(0, 0, 0); SA8(0, 0, 2); SA8(0, 0, 1); SA8(0, 0, 3);
  SB8(1, 1, 0); SB8(1, 1, 1); SB8(1, 1, 2); SB8(1, 1, 3);
  SA8(1, 1, 0); SA8(1, 1, 2);
  VMC6();  // completes oldest 8 = tile0
  __builtin_amdgcn_s_barrier();

  short8 bf[4][2];
#pragma unroll 1
  for (int u = 0; u < NK / 2; ++u) {
    int kt0 = 2 * u;
    bool last = (u == NK / 2 - 1);
    // ---- K-tile kt0 (buf0) ----
    LOADB8(0)
    PH8(0, 0, SA8(1, kt0 + 1, 1); SA8(1, kt0 + 1, 3), NOPS)
    PH8(0, 2, if (!last) { SB8(0, kt0 + 2, 0); SB8(0, kt0 + 2, 1); }, NOPS)
    PH8(0, 4, if (!last) { SB8(0, kt0 + 2, 2); SB8(0, kt0 + 2, 3); }, NOPS)
    PH8(0, 6, if (!last) { SA8(0, kt0 + 2, 0); SA8(0, kt0 + 2, 2); },
        if (last) VMC0(); else VMC6())
    // ---- K-tile kt0+1 (buf1) ----
    LOADB8(1)
    PH8(1, 0, if (!last) { SA8(0, kt0 + 2, 1); SA8(0, kt0 + 2, 3); }, NOPS)
    PH8(1, 2, if (!last) { SB8(1, kt0 + 3, 0); SB8(1, kt0 + 3, 1); }, NOPS)
    PH8(1, 4, if (!last) { SB8(1, kt0 + 3, 2); SB8(1, kt0 + 3, 3); }, NOPS)
    PH8(1, 6, if (!last) { SA8(1, kt0 + 3, 0); SA8(1, kt0 + 3, 2); },
        if (!last) VMC6())
  }
}

// ---------------- GEMM kernels ----------------

__global__ __launch_bounds__(512, 2) void ffn1_kernel(
    const unsigned short* __restrict__ xb, const unsigned short* __restrict__ w1t,
    const float* __restrict__ b1, const int* __restrict__ perm,
    const int* __restrict__ ntiles, const int* __restrict__ tile_e,
    const int* __restrict__ tile_base, const int* __restrict__ tile_len,
    unsigned short* __restrict__ interb) {
  int t = blockIdx.y;
  if (t >= *ntiles) return;
  int e = tile_e[t], base = tile_base[t], len = tile_len[t];
  int nb = blockIdx.x * 256;

  __shared__ unsigned short lA[2 * 16384];  // 64 KB
  __shared__ unsigned short lB[2 * 16384];  // 64 KB

  int tid = threadIdx.x;
  int wave = tid >> 6, lane = tid & 63;
  int lr = lane >> 3, l7 = lane & 7;
  int chunk = l7 ^ lr;  // pre-swizzled global source chunk

  const unsigned short* gAq[4];
  const unsigned short* gBq[4];
#pragma unroll
  for (int q = 0; q < 4; q++) {
    int rr = q * 64 + wave * 8 + lr;
    int token = perm[base + (rr < len ? rr : len - 1)];  // clamp (stores masked)
    gAq[q] = xb + (size_t)token * HD + chunk * 8;
    gBq[q] = w1t + ((size_t)e * ID + nb + rr) * HD + chunk * 8;
  }

  floatx4 acc[8][4];
#pragma unroll
  for (int i = 0; i < 8; i++)
#pragma unroll
    for (int j = 0; j < 4; j++) acc[i][j] = (floatx4){0.f, 0.f, 0.f, 0.f};

  gemm8phase<HD / 64>(gAq, gBq, lA, lB, wave, lane, acc);

  int c15 = lane & 15, q4 = lane >> 4;
  int wm = wave >> 2, wn = wave & 3;
#pragma unroll
  for (int i = 0; i < 8; i++) {
#pragma unroll
    for (int r = 0; r < 4; r++) {
      int tr = wm * 128 + i * 16 + q4 * 4 + r;
      if (tr >= len) continue;
      int token = perm[base + tr];
#pragma unroll
      for (int j = 0; j < 4; j++) {
        int col = nb + wn * 64 + j * 16 + c15;
        float v = acc[i][j][r] + b1[e * ID + col];
        v = 0.5f * v * (1.0f + erff(v * 0.70710678118654752f));  // exact GELU
        interb[(size_t)token * ID + col] = f2bf(v);
      }
    }
  }
}

__global__ __launch_bounds__(512, 2) void ffn2_kernel(
    const unsigned short* __restrict__ interb, const unsigned short* __restrict__ wot,
    const float* __restrict__ bo, const float* __restrict__ x, float* __restrict__ y) {
  int tm = blockIdx.y;          // 256-row token tile
  int nb = blockIdx.x * 256;    // 256-col tile of HD

  __shared__ unsigned short lA[2 * 16384];
  __shared__ unsigned short lB[2 * 16384];

  int tid = threadIdx.x;
  int wave = tid >> 6, lane = tid & 63;
  int lr = lane >> 3, l7 = lane & 7;
  int chunk = l7 ^ lr;

  const unsigned short* gAq[4];
  const unsigned short* gBq[4];
#pragma unroll
  for (int q = 0; q < 4; q++) {
    int rr = q * 64 + wave * 8 + lr;
    gAq[q] = interb + (size_t)(tm * 256 + rr) * ID + chunk * 8;
    gBq[q] = wot + (size_t)(nb + rr) * ID + chunk * 8;
  }

  floatx4 acc[8][4];
#pragma unroll
  for (int i = 0; i < 8; i++)
#pragma unroll
    for (int j = 0; j < 4; j++) acc[i][j] = (floatx4){0.f, 0.f, 0.f, 0.f};

  gemm8phase<ID / 64>(gAq, gBq, lA, lB, wave, lane, acc);

  int c15 = lane & 15, q4 = lane >> 4;
  int wm = wave >> 2, wn = wave & 3;
#pragma unroll
  for (int i = 0; i < 8; i++) {
#pragma unroll
    for (int r = 0; r < 4; r++) {
      int row = tm * 256 + wm * 128 + i * 16 + q4 * 4 + r;
#pragma unroll
      for (int j = 0; j < 4; j++) {
        int col = nb + wn * 64 + j * 16 + c15;
        float v = acc[i][j][r] + bo[col] + x[(size_t)row * HD + col];
        y[(size_t)row * HD + col] = v;  // pre-LN y staged in d_out
      }
    }
  }
}

__global__ void ln_kernel(float* __restrict__ y, const float* __restrict__ gamma,
                          const float* __restrict__ beta) {
  int row = blockIdx.x, t = threadIdx.x;
  int lane = t & 63, wave = t >> 6;
  float* yr = y + (size_t)row * HD;
  float4 v = *(const float4*)(yr + t * 4);
  float s = v.x + v.y + v.z + v.w;
  float ss = v.x * v.x + v.y * v.y + v.z * v.z + v.w * v.w;
#pragma unroll
  for (int m = 32; m >= 1; m >>= 1) {
    s += __shfl_xor(s, m, 64);
    ss += __shfl_xor(ss, m, 64);
  }
  __shared__ float sred[4], ssred[4];
  if (lane == 0) { sred[wave] = s; ssred[wave] = ss; }
  __syncthreads();
  s = sred[0] + sred[1] + sred[2] + sred[3];
  ss = ssred[0] + ssred[1] + ssred[2] + ssred[3];
  float mu = s * (1.0f / HD);
  float var = ss * (1.0f / HD) - mu * mu;
  float rs = rsqrtf(var + 1e-12f);
  float4 g = *(const float4*)(gamma + t * 4);
  float4 b = *(const float4*)(beta + t * 4);
  float4 o;
  o.x = (v.x - mu) * rs * g.x + b.x;
  o.y = (v.y - mu) * rs * g.y + b.y;
  o.z = (v.z - mu) * rs * g.z + b.z;
  o.w = (v.w - mu) * rs * g.w + b.w;
  *(float4*)(yr + t * 4) = o;
}

// ---------------- host launcher ----------------

extern "C" void kernel_launch(void* const* d_in, const int* in_sizes, int n_in,
                              void* d_out, int out_size, void* d_ws, size_t ws_size,
                              hipStream_t stream) {
  const float* x     = (const float*)d_in[0];
  const float* wr    = (const float*)d_in[1];
  const float* w1    = (const float*)d_in[2];
  const float* b1    = (const float*)d_in[3];
  const float* wo    = (const float*)d_in[4];
  const float* bo    = (const float*)d_in[5];
  const float* gamma = (const float*)d_in[6];
  const float* beta  = (const float*)d_in[7];
  float* out = (float*)d_out;

  char* p = (char*)d_ws;
  unsigned short* w1t = (unsigned short*)p; p += (size_t)NE * ID * HD * 2;   // 67 MB
  unsigned short* wot = (unsigned short*)p; p += (size_t)HD * ID * 2;        // 8.4 MB
  unsigned short* xb  = (unsigned short*)p; p += (size_t)NTOK * HD * 2;      // 16.8 MB
  unsigned short* interb = (unsigned short*)p; p += (size_t)NTOK * ID * 2;   // 67 MB
  int* eidx = (int*)p; p += (size_t)NTOK * 4;
  int* perm = (int*)p; p += (size_t)NTOK * 4;
  int* ints = (int*)p;
  int* ntiles    = ints;        // 1
  int* tile_e    = ints + 8;    // 40
  int* tile_base = ints + 80;   // 40
  int* tile_len  = ints + 152;  // 40

  router_kernel<<<NTOK / 4, 256, 0, stream>>>(x, wr, eidx, xb);
  transpose_cast_kernel<<<dim3(ID / 64, HD / 64, NE), 256, 0, stream>>>(w1, w1t, HD, ID);
  transpose_cast_kernel<<<dim3(HD / 64, ID / 64, 1), 256, 0, stream>>>(wo, wot, ID, HD);
  sort_kernel<<<1, SORTT, 0, stream>>>(eidx, ntiles, tile_e, tile_base, tile_len, perm);
  ffn1_kernel<<<dim3(ID / 256, MAXTILES), 512, 0, stream>>>(
      xb, w1t, b1, perm, ntiles, tile_e, tile_base, tile_len, interb);
  ffn2_kernel<<<dim3(HD / 256, NTOK / 256), 512, 0, stream>>>(interb, wot, bo, x, out);
  ln_kernel<<<NTOK, 256, 0, stream>>>(out, gamma, beta);
}